// Round 1
// baseline (5459.991 us; speedup 1.0000x reference)
//
#include <hip/hip_runtime.h>

#define NN 100000
#define EE 600000
#define DD 164
#define HH 2
#define DKK 82
#define EDIM 16
#define TDIM 8
#define STEP 30000
#define NC 20          // EE / STEP
#define FEAT 24        // EDIM + TDIM
#define HID 82         // D/2

__device__ __forceinline__ float fast_tanh(float x) {
    // tanh(x) = 1 - 2/(exp(2x)+1); v_exp + v_rcp, ~1e-6 abs err, saturates correctly
    float e = __expf(2.0f * x);
    return 1.0f - 2.0f * __builtin_amdgcn_rcpf(e + 1.0f);
}

__global__ void __launch_bounds__(256) zero_kernel(float4* __restrict__ p, int n4) {
    int i = blockIdx.x * 256 + threadIdx.x;
    if (i < n4) p[i] = make_float4(0.f, 0.f, 0.f, 0.f);
}

// escore[e*2+h] = exp(q[dst]·k[src] / sqrt(82) + rel_bias[h])
__global__ void __launch_bounds__(256) score_kernel(
    const float* __restrict__ q, const float* __restrict__ k,
    const int* __restrict__ ei, const float* __restrict__ rel_bias,
    float* __restrict__ escore)
{
    int e = blockIdx.x * 256 + threadIdx.x;
    if (e >= EE) return;
    int s = ei[e];        // src = edge_index[0]
    int d = ei[EE + e];   // dst = edge_index[1]
    const float4* qr = (const float4*)(q + (size_t)d * DD);
    const float4* kr = (const float4*)(k + (size_t)s * DD);
    float s0 = 0.f, s1 = 0.f;
    #pragma unroll 4
    for (int i = 0; i < 20; ++i) {            // dims 0..79 -> head 0
        float4 a = qr[i], b = kr[i];
        s0 += a.x * b.x; s0 += a.y * b.y; s0 += a.z * b.z; s0 += a.w * b.w;
    }
    {                                          // dims 80,81 | 82,83
        float4 a = qr[20], b = kr[20];
        s0 += a.x * b.x + a.y * b.y;
        s1 += a.z * b.z + a.w * b.w;
    }
    #pragma unroll 4
    for (int i = 21; i < 41; ++i) {           // dims 84..163 -> head 1
        float4 a = qr[i], b = kr[i];
        s1 += a.x * b.x; s1 += a.y * b.y; s1 += a.z * b.z; s1 += a.w * b.w;
    }
    const float inv_sqrt = 0.11043152607484654f;  // 1/sqrt(82)
    float rb0 = rel_bias[0], rb1 = rel_bias[1];
    escore[2 * e]     = __expf(s0 * inv_sqrt + rb0);
    escore[2 * e + 1] = __expf(s1 * inv_sqrt + rb1);
}

// chunksum[c*2+h] = sum over STEP edges of escore
__global__ void __launch_bounds__(256) chunksum_kernel(
    const float* __restrict__ escore, float* __restrict__ chunksum)
{
    int c = blockIdx.x, h = blockIdx.y;
    const float* base = escore + (size_t)c * STEP * 2 + h;
    float acc = 0.f;
    for (int i = threadIdx.x; i < STEP; i += 256) acc += base[2 * i];
    __shared__ float red[256];
    red[threadIdx.x] = acc;
    __syncthreads();
    for (int s2 = 128; s2 > 0; s2 >>= 1) {
        if (threadIdx.x < s2) red[threadIdx.x] += red[threadIdx.x + s2];
        __syncthreads();
    }
    if (threadIdx.x == 0) chunksum[c * 2 + h] = red[0];
}

// Per-edge FiLM MLP + modulation + att scaling + scatter-add.
// W1/W2/biases are wave-uniform accesses -> scalar loads feeding v_fmac.
__global__ void __launch_bounds__(256) main_kernel(
    const float* __restrict__ v, const int* __restrict__ ei,
    const float* __restrict__ edge_attr, const float* __restrict__ edge_time,
    const float* __restrict__ Wt, const float* __restrict__ bt,
    const float* __restrict__ W1, const float* __restrict__ b1,
    const float* __restrict__ W2, const float* __restrict__ b2,
    const float* __restrict__ escore, const float* __restrict__ chunksum,
    float* __restrict__ out)
{
    int e = blockIdx.x * 256 + threadIdx.x;
    if (e >= EE) return;
    int s = ei[e];
    int d = ei[EE + e];

    // ---- feat = [edge_attr(16), time*Wt+bt(8)] ----
    float feat[FEAT];
    const float4* ea4 = (const float4*)(edge_attr + (size_t)e * EDIM);
    #pragma unroll
    for (int i = 0; i < 4; ++i) {
        float4 a = ea4[i];
        feat[4 * i + 0] = a.x; feat[4 * i + 1] = a.y;
        feat[4 * i + 2] = a.z; feat[4 * i + 3] = a.w;
    }
    float t = edge_time[e];
    #pragma unroll
    for (int j = 0; j < TDIM; ++j) feat[EDIM + j] = t * Wt[j] + bt[j];

    // ---- hmid = relu(W1 @ feat + b1), held in VGPRs ----
    float hmid[HID];
    #pragma unroll
    for (int o = 0; o < HID; ++o) {
        float acc = b1[o];
        #pragma unroll
        for (int f = 0; f < FEAT; ++f) acc = fmaf(feat[f], W1[o * FEAT + f], acc);
        hmid[o] = fmaxf(acc, 0.f);
    }

    // ---- attention weights ----
    int c = e / STEP;
    float att0 = escore[2 * e]     / chunksum[2 * c];
    float att1 = escore[2 * e + 1] / chunksum[2 * c + 1];

    const float4* vrow4 = (const float4*)(v + (size_t)s * DD);
    float* orow = out + (size_t)d * DD;

    // ---- gb = W2 @ hmid + b2; gamma/beta -> vh -> att*vh -> scatter ----
    #pragma unroll 1
    for (int j = 0; j < 41; ++j) {   // 4 output dims per iteration
        float4 vv = vrow4[j];
        float vvals[4] = {vv.x, vv.y, vv.z, vv.w};
        float res[4];
        #pragma unroll
        for (int u = 0; u < 4; ++u) {
            int dd = 4 * j + u;
            float ga = b2[dd];
            float bb = b2[dd + DD];
            #pragma unroll
            for (int o = 0; o < HID; ++o) {
                ga = fmaf(hmid[o], W2[dd * HID + o], ga);
                bb = fmaf(hmid[o], W2[(dd + DD) * HID + o], bb);
            }
            float gamma = fast_tanh(ga);
            float beta  = fast_tanh(bb);
            float vh = vvals[u] * (1.f + gamma) + beta;
            float att = (dd < DKK) ? att0 : att1;
            res[u] = att * vh;
        }
        unsafeAtomicAdd(orow + 4 * j + 0, res[0]);
        unsafeAtomicAdd(orow + 4 * j + 1, res[1]);
        unsafeAtomicAdd(orow + 4 * j + 2, res[2]);
        unsafeAtomicAdd(orow + 4 * j + 3, res[3]);
    }
}

extern "C" void kernel_launch(void* const* d_in, const int* in_sizes, int n_in,
                              void* d_out, int out_size, void* d_ws, size_t ws_size,
                              hipStream_t stream) {
    const float* q   = (const float*)d_in[0];
    const float* k   = (const float*)d_in[1];
    const float* v   = (const float*)d_in[2];
    const int*   ei  = (const int*)d_in[3];
    const float* ea  = (const float*)d_in[4];
    const float* et  = (const float*)d_in[5];
    const float* Wt  = (const float*)d_in[6];
    const float* bt  = (const float*)d_in[7];
    const float* W1  = (const float*)d_in[8];
    const float* b1  = (const float*)d_in[9];
    const float* W2  = (const float*)d_in[10];
    const float* b2  = (const float*)d_in[11];
    const float* rb  = (const float*)d_in[12];
    float* out = (float*)d_out;

    float* escore   = (float*)d_ws;          // EE*2 floats = 4.8 MB
    float* chunksum = escore + 2 * EE;       // NC*HH floats

    int n4 = out_size / 4;                   // 16,400,000 / 4
    zero_kernel<<<(n4 + 255) / 256, 256, 0, stream>>>((float4*)out, n4);
    score_kernel<<<(EE + 255) / 256, 256, 0, stream>>>(q, k, ei, rb, escore);
    chunksum_kernel<<<dim3(NC, HH), 256, 0, stream>>>(escore, chunksum);
    main_kernel<<<(EE + 255) / 256, 256, 0, stream>>>(
        v, ei, ea, et, Wt, bt, W1, b1, W2, b2, escore, chunksum, out);
}